// Round 2
// baseline (2638.668 us; speedup 1.0000x reference)
//
#include <hip/hip_runtime.h>
#include <hip/hip_bf16.h>

#define H 128
#define RBF 64

// ---------------------------------------------------------------- utilities
// LN over a 128-wide row, one row per 128-thread block.
__global__ __launch_bounds__(128) void ln_rows(const float* __restrict__ X,
                                               const float* __restrict__ g,
                                               const float* __restrict__ bb,
                                               float* __restrict__ Y, int N) {
  __shared__ float sh[4];
  const int row = blockIdx.x;
  const int j = threadIdx.x;
  float x = X[(size_t)row * H + j];
  float s = x, q = x * x;
#pragma unroll
  for (int m = 32; m; m >>= 1) {
    s += __shfl_xor(s, m, 64);
    q += __shfl_xor(q, m, 64);
  }
  if ((j & 63) == 0) { sh[(j >> 6) * 2] = s; sh[(j >> 6) * 2 + 1] = q; }
  __syncthreads();
  s = sh[0] + sh[2];
  q = sh[1] + sh[3];
  const float mu = s * 0.0078125f;
  const float var = q * 0.0078125f - mu * mu;
  const float rs = rsqrtf(var + 1e-5f);
  Y[(size_t)row * H + j] = (x - mu) * rs * g[j] + bb[j];
}

// conv_k (o,i,dx,dy,dz) -> Kt[tap][i][o]
__global__ void transpose_k(const float* __restrict__ K, float* __restrict__ Kt) {
  const int idx = blockIdx.x * 256 + threadIdx.x;
  const int total = H * H * 27;
  if (idx >= total) return;
  const int tap = idx % 27;
  const int rem = idx / 27;
  const int i = rem % H;
  const int o = rem / H;
  Kt[((size_t)tap * H + i) * H + o] = K[idx];
}

// ----------------------------------------------- counting-sort (CSR builder)
__global__ __launch_bounds__(256) void k_hist(const int* __restrict__ dst, int E,
                                              int* __restrict__ cnt) {
  int e = blockIdx.x * 256 + threadIdx.x;
  const int stride = gridDim.x * 256;
  for (; e < E; e += stride) atomicAdd(&cnt[dst[e]], 1);
}

__global__ __launch_bounds__(256) void k_blocksum(const int* __restrict__ cnt,
                                                  int* __restrict__ bsum) {
  __shared__ int sh[256];
  const int t = threadIdx.x;
  sh[t] = cnt[blockIdx.x * 256 + t];
  __syncthreads();
#pragma unroll
  for (int o = 128; o; o >>= 1) {
    if (t < o) sh[t] += sh[t + o];
    __syncthreads();
  }
  if (!t) bsum[blockIdx.x] = sh[0];
}

// exclusive scan of <=256 block sums, single block
__global__ __launch_bounds__(256) void k_scan_bsum(const int* __restrict__ bsum,
                                                   int* __restrict__ bpre, int NB) {
  __shared__ int sh[256];
  const int t = threadIdx.x;
  const int v = (t < NB) ? bsum[t] : 0;
  sh[t] = v;
  __syncthreads();
  for (int o = 1; o < 256; o <<= 1) {
    const int u = (t >= o) ? sh[t - o] : 0;
    __syncthreads();
    sh[t] += u;
    __syncthreads();
  }
  if (t < NB) bpre[t] = sh[t] - v;
}

__global__ __launch_bounds__(256) void k_apply(const int* __restrict__ cnt,
                                               const int* __restrict__ bpre,
                                               int* __restrict__ rowptr,
                                               int* __restrict__ cursor, int N) {
  __shared__ int sh[256];
  const int t = threadIdx.x;
  const int i = blockIdx.x * 256 + t;
  const int v = cnt[i];  // zero-padded past N
  sh[t] = v;
  __syncthreads();
  for (int o = 1; o < 256; o <<= 1) {
    const int u = (t >= o) ? sh[t - o] : 0;
    __syncthreads();
    sh[t] += u;
    __syncthreads();
  }
  const int excl = sh[t] - v + bpre[blockIdx.x];
  if (i <= N) {
    rowptr[i] = excl;
    if (i < N) cursor[i] = excl;
  }
}

__global__ __launch_bounds__(256) void k_perm(const int* __restrict__ dst, int E,
                                              int* __restrict__ cursor,
                                              int* __restrict__ perm) {
  int e = blockIdx.x * 256 + threadIdx.x;
  const int stride = gridDim.x * 256;
  for (; e < E; e += stride) {
    const int p = atomicAdd(&cursor[dst[e]], 1);
    perm[p] = e;
  }
}

// ------------------------------------------- node projection: Y = [LN](X) @ W
template <bool DO_LN>
__global__ __launch_bounds__(256) void proj_kernel(const float* __restrict__ X,
                                                   const float* __restrict__ W,
                                                   const float* __restrict__ g,
                                                   const float* __restrict__ bb,
                                                   float* __restrict__ Y, int N) {
  __shared__ float At[128 * 68];
  const int row0 = blockIdx.x * 64;
  const int t = threadIdx.x;
  const int lk = (t & 31) * 4;
  const int lr = t >> 5;
  float4 g4 = {0, 0, 0, 0}, b4 = {0, 0, 0, 0};
  if (DO_LN) {
    g4 = *(const float4*)(g + lk);
    b4 = *(const float4*)(bb + lk);
  }
#pragma unroll
  for (int p = 0; p < 8; ++p) {
    const int r = lr + p * 8;
    const int row = row0 + r;
    float4 xv = make_float4(0.f, 0.f, 0.f, 0.f);
    if (row < N) xv = *(const float4*)(X + (size_t)row * H + lk);
    if (DO_LN) {
      float s = xv.x + xv.y + xv.z + xv.w;
      float q = xv.x * xv.x + xv.y * xv.y + xv.z * xv.z + xv.w * xv.w;
#pragma unroll
      for (int m = 16; m; m >>= 1) {
        s += __shfl_xor(s, m, 64);
        q += __shfl_xor(q, m, 64);
      }
      const float mu = s * 0.0078125f;
      const float var = q * 0.0078125f - mu * mu;
      const float rs = rsqrtf(var + 1e-5f);
      xv.x = (xv.x - mu) * rs * g4.x + b4.x;
      xv.y = (xv.y - mu) * rs * g4.y + b4.y;
      xv.z = (xv.z - mu) * rs * g4.z + b4.z;
      xv.w = (xv.w - mu) * rs * g4.w + b4.w;
    }
    At[(lk + 0) * 68 + r] = xv.x;
    At[(lk + 1) * 68 + r] = xv.y;
    At[(lk + 2) * 68 + r] = xv.z;
    At[(lk + 3) * 68 + r] = xv.w;
  }
  __syncthreads();
  const int tc = t & 15;
  const int tr = t >> 4;
  float acc[4][8];
#pragma unroll
  for (int i = 0; i < 4; ++i)
#pragma unroll
    for (int c = 0; c < 8; ++c) acc[i][c] = 0.f;
  const float* wbase = W + tc * 8;
#pragma unroll 4
  for (int k = 0; k < 128; ++k) {
    const float4 a4 = *(const float4*)(At + k * 68 + tr * 4);
    const float4 w0 = *(const float4*)(wbase + k * H);
    const float4 w1 = *(const float4*)(wbase + k * H + 4);
    const float av[4] = {a4.x, a4.y, a4.z, a4.w};
#pragma unroll
    for (int i = 0; i < 4; ++i) {
      acc[i][0] += av[i] * w0.x; acc[i][1] += av[i] * w0.y;
      acc[i][2] += av[i] * w0.z; acc[i][3] += av[i] * w0.w;
      acc[i][4] += av[i] * w1.x; acc[i][5] += av[i] * w1.y;
      acc[i][6] += av[i] * w1.z; acc[i][7] += av[i] * w1.w;
    }
  }
#pragma unroll
  for (int i = 0; i < 4; ++i) {
    const int row = row0 + tr * 4 + i;
    if (row < N) {
      float4 o0 = {acc[i][0], acc[i][1], acc[i][2], acc[i][3]};
      float4 o1 = {acc[i][4], acc[i][5], acc[i][6], acc[i][7]};
      float* yp = Y + (size_t)row * H + tc * 8;
      *(float4*)yp = o0;
      *(float4*)(yp + 4) = o1;
    }
  }
}

// -------------------------------------------------------- fused edge gather
// out[n] = sum_{e: dst[e]==n} P[src[e]] * (ea[e] @ We) * ew[e]
// optionally + fused LN + base + skip. Wave = (node, col-half); CSR order.
template <bool FUSE_LN>
__global__ __launch_bounds__(256, 2) void edge_gather(
    const float* __restrict__ P, const int* __restrict__ src,
    const float* __restrict__ ew, const float* __restrict__ ea,
    const float* __restrict__ We, const int* __restrict__ rowptr,
    const int* __restrict__ perm, const float* __restrict__ base,
    const float* __restrict__ skip, const float* __restrict__ g,
    const float* __restrict__ bb, float* __restrict__ out, int N) {
  __shared__ float red[4][2];
  const int t = threadIdx.x;
  const int w = t >> 6, lane = t & 63;
  const int node = blockIdx.x * 2 + (w >> 1);
  const int col = (w & 1) * 64 + lane;
  // pin the 64 filter coefficients for this column in VGPRs
  float we[RBF];
#pragma unroll
  for (int k = 0; k < RBF; ++k) we[k] = We[k * H + col];
#pragma unroll
  for (int k = 0; k < RBF; ++k) asm volatile("" : "+v"(we[k]));

  float acc = 0.f;
  if (node < N) {
    const int beg = __builtin_amdgcn_readfirstlane(rowptr[node]);
    const int end = __builtin_amdgcn_readfirstlane(rowptr[node + 1]);
    int i = beg;
    for (; i + 1 < end; i += 2) {  // 2-edge pipeline
      const int e0 = __builtin_amdgcn_readfirstlane(perm[i]);
      const int e1 = __builtin_amdgcn_readfirstlane(perm[i + 1]);
      const float* ea0 = ea + (size_t)e0 * RBF;
      const float* ea1 = ea + (size_t)e1 * RBF;
      const int s0 = __builtin_amdgcn_readfirstlane(src[e0]);
      const int s1 = __builtin_amdgcn_readfirstlane(src[e1]);
      const float p0 = P[(size_t)s0 * H + col];
      const float p1 = P[(size_t)s1 * H + col];
      const float w0 = ew[e0], w1 = ew[e1];
      float f00 = 0, f01 = 0, f02 = 0, f03 = 0;
      float f10 = 0, f11 = 0, f12 = 0, f13 = 0;
#pragma unroll
      for (int k = 0; k < RBF; k += 4) {
        f00 += ea0[k] * we[k];     f01 += ea0[k + 1] * we[k + 1];
        f02 += ea0[k + 2] * we[k + 2]; f03 += ea0[k + 3] * we[k + 3];
        f10 += ea1[k] * we[k];     f11 += ea1[k + 1] * we[k + 1];
        f12 += ea1[k + 2] * we[k + 2]; f13 += ea1[k + 3] * we[k + 3];
      }
      acc += p0 * (((f00 + f01) + (f02 + f03)) * w0);
      acc += p1 * (((f10 + f11) + (f12 + f13)) * w1);
    }
    for (; i < end; ++i) {
      const int e0 = __builtin_amdgcn_readfirstlane(perm[i]);
      const float* ea0 = ea + (size_t)e0 * RBF;
      const int s0 = __builtin_amdgcn_readfirstlane(src[e0]);
      const float p0 = P[(size_t)s0 * H + col];
      const float w0 = ew[e0];
      float f00 = 0, f01 = 0, f02 = 0, f03 = 0;
#pragma unroll
      for (int k = 0; k < RBF; k += 4) {
        f00 += ea0[k] * we[k];     f01 += ea0[k + 1] * we[k + 1];
        f02 += ea0[k + 2] * we[k + 2]; f03 += ea0[k + 3] * we[k + 3];
      }
      acc += p0 * (((f00 + f01) + (f02 + f03)) * w0);
    }
  }
  if (FUSE_LN) {
    float s = acc, q = acc * acc;
#pragma unroll
    for (int m = 32; m; m >>= 1) {
      s += __shfl_xor(s, m, 64);
      q += __shfl_xor(q, m, 64);
    }
    if (!lane) { red[w][0] = s; red[w][1] = q; }
    __syncthreads();
    if (node < N) {
      const int w2 = w ^ 1;
      s = red[w][0] + red[w2][0];
      q = red[w][1] + red[w2][1];
      const float mu = s * 0.0078125f;
      const float var = q * 0.0078125f - mu * mu;
      const float rs = rsqrtf(var + 1e-5f);
      const size_t idx = (size_t)node * H + col;
      out[idx] = base[idx] + ((acc - mu) * rs * g[col] + bb[col]) + skip[idx];
    }
  } else if (node < N) {
    out[(size_t)node * H + col] = acc;
  }
}

// ----------------------------------------------------------------- conv3d
__global__ __launch_bounds__(256) void conv3d(const float* __restrict__ Min,
                                              const float* __restrict__ Kt,
                                              const float* __restrict__ bias,
                                              float* __restrict__ Mout) {
  __shared__ float in_s[193 * 68];
  const int b = blockIdx.x >> 3;
  const int x = blockIdx.x & 7;
  const int t = threadIdx.x;
  const int tc = t & 15;
  const int tr = t >> 4;
  float acc[4][8];
  {
    const float4 bs0 = *(const float4*)(bias + tc * 8);
    const float4 bs1 = *(const float4*)(bias + tc * 8 + 4);
#pragma unroll
    for (int vi = 0; vi < 4; ++vi) {
      acc[vi][0] = bs0.x; acc[vi][1] = bs0.y; acc[vi][2] = bs0.z; acc[vi][3] = bs0.w;
      acc[vi][4] = bs1.x; acc[vi][5] = bs1.y; acc[vi][6] = bs1.z; acc[vi][7] = bs1.w;
    }
  }
  for (int u = t; u < 68; u += 256) in_s[192 * 68 + u] = 0.f;

  for (int pass = 0; pass < 2; ++pass) {
    __syncthreads();
#pragma unroll
    for (int it = 0; it < 12; ++it) {
      const int r = (t >> 4) + it * 16;
      const int c4 = (t & 15) * 4;
      const int xs = r >> 6;
      const int yz = r & 63;
      const int gx = x + xs - 1;
      float4 val = make_float4(0.f, 0.f, 0.f, 0.f);
      if (gx >= 0 && gx < 8) {
        const int row = (b * 8 + gx) * 64 + yz;
        val = *(const float4*)(Min + (size_t)row * H + pass * 64 + c4);
      }
      *(float4*)(in_s + r * 68 + c4) = val;
    }
    __syncthreads();

    for (int tap = 0; tap < 27; ++tap) {
      const int dx = tap / 9, dy = (tap / 3) % 3, dz = tap % 3;
      int rp[4];
#pragma unroll
      for (int vi = 0; vi < 4; ++vi) {
        const int v = tr * 4 + vi;
        const int y = v >> 3, z = v & 7;
        const int ny = y + dy - 1, nz = z + dz - 1;
        const bool ok = (ny >= 0 && ny < 8 && nz >= 0 && nz < 8);
        rp[vi] = ok ? (dx * 64 + ny * 8 + nz) * 68 : 192 * 68;
      }
      const float* wbase = Kt + ((size_t)tap * H + pass * 64) * H + tc * 8;
#pragma unroll 4
      for (int kk = 0; kk < 64; ++kk) {
        const float4 w0 = *(const float4*)(wbase + (size_t)kk * H);
        const float4 w1 = *(const float4*)(wbase + (size_t)kk * H + 4);
        float iv[4];
#pragma unroll
        for (int vi = 0; vi < 4; ++vi) iv[vi] = in_s[rp[vi] + kk];
#pragma unroll
        for (int vi = 0; vi < 4; ++vi) {
          acc[vi][0] += iv[vi] * w0.x; acc[vi][1] += iv[vi] * w0.y;
          acc[vi][2] += iv[vi] * w0.z; acc[vi][3] += iv[vi] * w0.w;
          acc[vi][4] += iv[vi] * w1.x; acc[vi][5] += iv[vi] * w1.y;
          acc[vi][6] += iv[vi] * w1.z; acc[vi][7] += iv[vi] * w1.w;
        }
      }
    }
  }
#pragma unroll
  for (int vi = 0; vi < 4; ++vi) {
    const int v = tr * 4 + vi;
    float* op = Mout + ((size_t)((b * 8 + x) * 64 + v)) * H + tc * 8;
    float4 o0 = {acc[vi][0], acc[vi][1], acc[vi][2], acc[vi][3]};
    float4 o1 = {acc[vi][4], acc[vi][5], acc[vi][6], acc[vi][7]};
    *(float4*)op = o0;
    *(float4*)(op + 4) = o1;
  }
}

// ------------------------------------------------------------------ driver
static inline void build_csr(const int* dst, int E, int N, int* cnt, int* bsum,
                             int* bpre, int* rowptr, int* cursor, int* perm,
                             hipStream_t stream) {
  const int NB = (N + 256) / 256;  // covers N+1 entries
  hipMemsetAsync(cnt, 0, (size_t)NB * 256 * sizeof(int), stream);
  k_hist<<<1024, 256, 0, stream>>>(dst, E, cnt);
  k_blocksum<<<NB, 256, 0, stream>>>(cnt, bsum);
  k_scan_bsum<<<1, 256, 0, stream>>>(bsum, bpre, NB);
  k_apply<<<NB, 256, 0, stream>>>(cnt, bpre, rowptr, cursor, N);
  k_perm<<<1024, 256, 0, stream>>>(dst, E, cursor, perm);
}

extern "C" void kernel_launch(void* const* d_in, const int* in_sizes, int n_in,
                              void* d_out, int out_size, void* d_ws, size_t ws_size,
                              hipStream_t stream) {
  const float* a_x = (const float*)d_in[0];
  const float* m_x = (const float*)d_in[1];
  const int* aa_idx = (const int*)d_in[2];
  const int* a2m_src = (const int*)d_in[3];
  const int* a2m_dst = (const int*)d_in[4];
  const int* m2a_src = (const int*)d_in[5];
  const int* m2a_dst = (const int*)d_in[6];
  const float* aa_w = (const float*)d_in[7];
  const float* a2m_w = (const float*)d_in[8];
  const float* m2a_w = (const float*)d_in[9];
  const float* aa_ea = (const float*)d_in[10];
  const float* a2m_ea = (const float*)d_in[11];
  const float* m2a_ea = (const float*)d_in[12];
  const float* W_short = (const float*)d_in[13];
  const float* We_short = (const float*)d_in[14];
  const float* W_a2m = (const float*)d_in[15];
  const float* We_a2m = (const float*)d_in[16];
  const float* W_m2a = (const float*)d_in[17];
  const float* We_m2a = (const float*)d_in[18];
  const float* conv_k = (const float*)d_in[19];
  const float* conv_b = (const float*)d_in[20];
  const float* g_short = (const float*)d_in[21];
  const float* b_short = (const float*)d_in[22];
  const float* g_long = (const float*)d_in[23];
  const float* b_long = (const float*)d_in[24];
  const float* g_a2m = (const float*)d_in[25];
  const float* b_a2m = (const float*)d_in[26];
  const float* g_m2a = (const float*)d_in[27];
  const float* b_m2a = (const float*)d_in[28];

  const int NA = in_sizes[0] / H;
  const int NM = in_sizes[1] / H;
  const int E_AA = in_sizes[2] / 2;
  const int E_AM = in_sizes[3];
  const int E_MA = in_sizes[5];
  const int* aa_src = aa_idx;
  const int* aa_dst = aa_idx + E_AA;

  float* ws = (float*)d_ws;
  float* p_buf = ws;                         // NA*H
  float* m1_buf = p_buf + (size_t)NA * H;    // NM*H
  float* m2_buf = m1_buf + (size_t)NM * H;   // NM*H
  float* a2_buf = m2_buf + (size_t)NM * H;   // NA*H
  float* kt = a2_buf + (size_t)NA * H;       // 27*128*128
  int* iws = (int*)(kt + (size_t)27 * H * H);
  int* perm_aa = iws;                 iws += E_AA;
  int* perm_a2m = iws;                iws += E_AM;
  int* perm_m2a = iws;                iws += E_MA;
  const int PADN = ((NA + 256) / 256) * 256;  // padded count-array size
  int* rp_aa = iws;                   iws += NA + 1;
  int* rp_a2m = iws;                  iws += NM + 1;
  int* rp_m2a = iws;                  iws += NA + 1;
  int* cnt = iws;                     iws += PADN;
  int* cursor = iws;                  iws += PADN;
  int* bsum = iws;                    iws += 256;
  int* bpre = iws;                    iws += 256;

  float* out_a = (float*)d_out;
  float* out_m = out_a + (size_t)NA * H;

  // CSR builds (serialized on stream; cnt/cursor scratch reused)
  build_csr(aa_dst, E_AA, NA, cnt, bsum, bpre, rp_aa, cursor, perm_aa, stream);
  build_csr(a2m_dst, E_AM, NM, cnt, bsum, bpre, rp_a2m, cursor, perm_a2m, stream);
  build_csr(m2a_dst, E_MA, NA, cnt, bsum, bpre, rp_m2a, cursor, perm_m2a, stream);

  transpose_k<<<(H * H * 27 + 255) / 256, 256, 0, stream>>>(conv_k, kt);
  ln_rows<<<NM, 128, 0, stream>>>(m_x, g_long, b_long, m1_buf, NM);

  // P_short = LN(a_x) @ W_short
  proj_kernel<true><<<(NA + 63) / 64, 256, 0, stream>>>(a_x, W_short, g_short,
                                                        b_short, p_buf, NA);
  // a = gather_aa(P_short)  (raw, no LN)
  edge_gather<false><<<(NA + 1) / 2, 256, 0, stream>>>(
      p_buf, aa_src, aa_w, aa_ea, We_short, rp_aa, perm_aa, nullptr, nullptr,
      nullptr, nullptr, a2_buf, NA);
  // m = conv3d(LN(m_x))
  conv3d<<<(NM / 64), 256, 0, stream>>>(m1_buf, kt, conv_b, m2_buf);

  // P_a2m = a @ W_a2m
  proj_kernel<false><<<(NA + 63) / 64, 256, 0, stream>>>(a2_buf, W_a2m, nullptr,
                                                         nullptr, p_buf, NA);
  // out_m = m + LN(gather_a2m(P_a2m)) + m_x
  edge_gather<true><<<(NM + 1) / 2, 256, 0, stream>>>(
      p_buf, a2m_src, a2m_w, a2m_ea, We_a2m, rp_a2m, perm_a2m, m2_buf, m_x,
      g_a2m, b_a2m, out_m, NM);
  // P_m2a = m @ W_m2a
  proj_kernel<false><<<(NM + 63) / 64, 256, 0, stream>>>(m2_buf, W_m2a, nullptr,
                                                         nullptr, m1_buf, NM);
  // out_a = a + LN(gather_m2a(P_m2a)) + a_x
  edge_gather<true><<<(NA + 1) / 2, 256, 0, stream>>>(
      m1_buf, m2a_src, m2a_w, m2a_ea, We_m2a, rp_m2a, perm_m2a, a2_buf, a_x,
      g_m2a, b_m2a, out_a, NA);
}

// Round 3
// 2046.924 us; speedup vs baseline: 1.2891x; 1.2891x over previous
//
#include <hip/hip_runtime.h>
#include <hip/hip_bf16.h>

#define H 128
#define RBF 64

typedef __attribute__((ext_vector_type(8))) short bf16x8;
typedef __attribute__((ext_vector_type(4))) float f32x4;

__device__ inline short f2bf(float f) {
  union { float f; unsigned u; } v; v.f = f;
  const unsigned r = (v.u + 0x7FFFu + ((v.u >> 16) & 1u)) >> 16;
  return (short)r;
}

// ---------------------------------------------------------------- utilities
__global__ __launch_bounds__(128) void ln_rows(const float* __restrict__ X,
                                               const float* __restrict__ g,
                                               const float* __restrict__ bb,
                                               float* __restrict__ Y, int N) {
  __shared__ float sh[4];
  const int row = blockIdx.x;
  const int j = threadIdx.x;
  float x = X[(size_t)row * H + j];
  float s = x, q = x * x;
#pragma unroll
  for (int m = 32; m; m >>= 1) {
    s += __shfl_xor(s, m, 64);
    q += __shfl_xor(q, m, 64);
  }
  if ((j & 63) == 0) { sh[(j >> 6) * 2] = s; sh[(j >> 6) * 2 + 1] = q; }
  __syncthreads();
  s = sh[0] + sh[2];
  q = sh[1] + sh[3];
  const float mu = s * 0.0078125f;
  const float var = q * 0.0078125f - mu * mu;
  const float rs = rsqrtf(var + 1e-5f);
  Y[(size_t)row * H + j] = (x - mu) * rs * g[j] + bb[j];
}

// conv_k (o,i,dx,dy,dz) -> Kt[tap][i][o]
__global__ void transpose_k(const float* __restrict__ K, float* __restrict__ Kt) {
  const int idx = blockIdx.x * 256 + threadIdx.x;
  const int total = H * H * 27;
  if (idx >= total) return;
  const int tap = idx % 27;
  const int rem = idx / 27;
  const int i = rem % H;
  const int o = rem / H;
  Kt[((size_t)tap * H + i) * H + o] = K[idx];
}

// We[64][128] f32 -> frag-layout bf16: Web[((h*8+c)*64+lane)*8+j]
__global__ __launch_bounds__(256) void pack_we(const float* __restrict__ We,
                                               short* __restrict__ Web) {
  const int id = blockIdx.x * 256 + threadIdx.x;
  if (id >= 1024) return;
  const int f = id >> 6, l = id & 63;
  const int h = f >> 3, c = f & 7;
  const int col = (c << 4) + (l & 15);
  const int k0 = h * 32 + (l >> 4) * 8;
  short* o = Web + (size_t)id * 8;
#pragma unroll
  for (int j = 0; j < 8; ++j) o[j] = f2bf(We[(k0 + j) * H + col]);
}

// ----------------------------------------------- counting-sort (CSR builder)
__global__ __launch_bounds__(256) void k_hist(const int* __restrict__ dst, int E,
                                              int* __restrict__ cnt) {
  int e = blockIdx.x * 256 + threadIdx.x;
  const int stride = gridDim.x * 256;
  for (; e < E; e += stride) atomicAdd(&cnt[dst[e]], 1);
}

__global__ __launch_bounds__(256) void k_blocksum(const int* __restrict__ cnt,
                                                  int* __restrict__ bsum) {
  __shared__ int sh[256];
  const int t = threadIdx.x;
  sh[t] = cnt[blockIdx.x * 256 + t];
  __syncthreads();
#pragma unroll
  for (int o = 128; o; o >>= 1) {
    if (t < o) sh[t] += sh[t + o];
    __syncthreads();
  }
  if (!t) bsum[blockIdx.x] = sh[0];
}

__global__ __launch_bounds__(256) void k_scan_bsum(const int* __restrict__ bsum,
                                                   int* __restrict__ bpre, int NB) {
  __shared__ int sh[256];
  const int t = threadIdx.x;
  const int v = (t < NB) ? bsum[t] : 0;
  sh[t] = v;
  __syncthreads();
  for (int o = 1; o < 256; o <<= 1) {
    const int u = (t >= o) ? sh[t - o] : 0;
    __syncthreads();
    sh[t] += u;
    __syncthreads();
  }
  if (t < NB) bpre[t] = sh[t] - v;
}

__global__ __launch_bounds__(256) void k_apply(const int* __restrict__ cnt,
                                               const int* __restrict__ bpre,
                                               int* __restrict__ rowptr,
                                               int* __restrict__ cursor, int N) {
  __shared__ int sh[256];
  const int t = threadIdx.x;
  const int i = blockIdx.x * 256 + t;
  const int v = cnt[i];
  sh[t] = v;
  __syncthreads();
  for (int o = 1; o < 256; o <<= 1) {
    const int u = (t >= o) ? sh[t - o] : 0;
    __syncthreads();
    sh[t] += u;
    __syncthreads();
  }
  const int excl = sh[t] - v + bpre[blockIdx.x];
  if (i <= N) {
    rowptr[i] = excl;
    if (i < N) cursor[i] = excl;
  }
}

// also pre-permute src and ew to kill double indirection in the gather
__global__ __launch_bounds__(256) void k_perm(const int* __restrict__ dst,
                                              const int* __restrict__ src,
                                              const float* __restrict__ ew, int E,
                                              int* __restrict__ cursor,
                                              int* __restrict__ perm,
                                              int* __restrict__ srcp,
                                              float* __restrict__ ewp) {
  int e = blockIdx.x * 256 + threadIdx.x;
  const int stride = gridDim.x * 256;
  for (; e < E; e += stride) {
    const int p = atomicAdd(&cursor[dst[e]], 1);
    perm[p] = e;
    srcp[p] = src[e];
    ewp[p] = ew[e];
  }
}

// ------------------------------------------- node projection: Y = [LN](X) @ W
template <bool DO_LN>
__global__ __launch_bounds__(256) void proj_kernel(const float* __restrict__ X,
                                                   const float* __restrict__ W,
                                                   const float* __restrict__ g,
                                                   const float* __restrict__ bb,
                                                   float* __restrict__ Y, int N) {
  __shared__ float At[128 * 68];
  const int row0 = blockIdx.x * 64;
  const int t = threadIdx.x;
  const int lk = (t & 31) * 4;
  const int lr = t >> 5;
  float4 g4 = {0, 0, 0, 0}, b4 = {0, 0, 0, 0};
  if (DO_LN) {
    g4 = *(const float4*)(g + lk);
    b4 = *(const float4*)(bb + lk);
  }
#pragma unroll
  for (int p = 0; p < 8; ++p) {
    const int r = lr + p * 8;
    const int row = row0 + r;
    float4 xv = make_float4(0.f, 0.f, 0.f, 0.f);
    if (row < N) xv = *(const float4*)(X + (size_t)row * H + lk);
    if (DO_LN) {
      float s = xv.x + xv.y + xv.z + xv.w;
      float q = xv.x * xv.x + xv.y * xv.y + xv.z * xv.z + xv.w * xv.w;
#pragma unroll
      for (int m = 16; m; m >>= 1) {
        s += __shfl_xor(s, m, 64);
        q += __shfl_xor(q, m, 64);
      }
      const float mu = s * 0.0078125f;
      const float var = q * 0.0078125f - mu * mu;
      const float rs = rsqrtf(var + 1e-5f);
      xv.x = (xv.x - mu) * rs * g4.x + b4.x;
      xv.y = (xv.y - mu) * rs * g4.y + b4.y;
      xv.z = (xv.z - mu) * rs * g4.z + b4.z;
      xv.w = (xv.w - mu) * rs * g4.w + b4.w;
    }
    At[(lk + 0) * 68 + r] = xv.x;
    At[(lk + 1) * 68 + r] = xv.y;
    At[(lk + 2) * 68 + r] = xv.z;
    At[(lk + 3) * 68 + r] = xv.w;
  }
  __syncthreads();
  const int tc = t & 15;
  const int tr = t >> 4;
  float acc[4][8];
#pragma unroll
  for (int i = 0; i < 4; ++i)
#pragma unroll
    for (int c = 0; c < 8; ++c) acc[i][c] = 0.f;
  const float* wbase = W + tc * 8;
#pragma unroll 4
  for (int k = 0; k < 128; ++k) {
    const float4 a4 = *(const float4*)(At + k * 68 + tr * 4);
    const float4 w0 = *(const float4*)(wbase + k * H);
    const float4 w1 = *(const float4*)(wbase + k * H + 4);
    const float av[4] = {a4.x, a4.y, a4.z, a4.w};
#pragma unroll
    for (int i = 0; i < 4; ++i) {
      acc[i][0] += av[i] * w0.x; acc[i][1] += av[i] * w0.y;
      acc[i][2] += av[i] * w0.z; acc[i][3] += av[i] * w0.w;
      acc[i][4] += av[i] * w1.x; acc[i][5] += av[i] * w1.y;
      acc[i][6] += av[i] * w1.z; acc[i][7] += av[i] * w1.w;
    }
  }
#pragma unroll
  for (int i = 0; i < 4; ++i) {
    const int row = row0 + tr * 4 + i;
    if (row < N) {
      float4 o0 = {acc[i][0], acc[i][1], acc[i][2], acc[i][3]};
      float4 o1 = {acc[i][4], acc[i][5], acc[i][6], acc[i][7]};
      float* yp = Y + (size_t)row * H + tc * 8;
      *(float4*)yp = o0;
      *(float4*)(yp + 4) = o1;
    }
  }
}

// ----------------------------------------- tiled MFMA edge gather (CSR, LDS)
// Block owns 32 dst nodes. 16-edge tiles: F = bf16(ea_tile) @ Web via MFMA;
// msg = F * ew * P[src]; ds_add_f32 into acc[32][132]; fused LN epilogue.
template <bool FUSE_LN>
__global__ __launch_bounds__(256, 2) void gather_mfma(
    const float* __restrict__ P, const short* __restrict__ Web,
    const float* __restrict__ ea, const int* __restrict__ perm,
    const int* __restrict__ srcp, const float* __restrict__ ewp,
    const int* __restrict__ rowptr, int E, int N,
    const float* __restrict__ base, const float* __restrict__ skip,
    const float* __restrict__ g, const float* __restrict__ bb,
    float* __restrict__ out) {
  __shared__ float acc[32 * 132];
  __shared__ int rp_s[33];
  const int t = threadIdx.x;
  const int w = t >> 6, lane = t & 63;
  const int n0 = blockIdx.x * 32;
  if (t < 33) rp_s[t] = rowptr[min(n0 + t, N)];
  for (int u = t; u < 32 * 132; u += 256) acc[u] = 0.f;
  __syncthreads();
  const int beg = rp_s[0], end = rp_s[32];
  const int ntiles = (end - beg + 15) >> 4;

  // B fragments: 16 x bf16x8 (64 VGPRs), frag f = h*8+c
  bf16x8 bf[16];
#pragma unroll
  for (int f = 0; f < 16; ++f)
    bf[f] = *(const bf16x8*)(Web + ((size_t)((f << 6) + lane)) * 8);

  const int l15 = lane & 15;
  const int lg = lane >> 4;
  const int rbase = lg * 4;

  for (int tt = w; tt < ntiles; tt += 4) {
    const int j0 = beg + (tt << 4);
    // ---- A fragments: lane holds ea row (j0 + l15), k = lg*8.. (+32 half)
    const int ja = j0 + l15;
    const bool av = ja < end;
    const int pe = perm[min(ja, E - 1)];
    const float* ear = ea + (size_t)pe * RBF + lg * 8;
    float4 a00 = make_float4(0.f, 0.f, 0.f, 0.f);
    float4 a01 = a00, a10 = a00, a11 = a00;
    if (av) {
      a00 = *(const float4*)(ear);
      a01 = *(const float4*)(ear + 4);
      a10 = *(const float4*)(ear + 32);
      a11 = *(const float4*)(ear + 36);
    }
    bf16x8 af0, af1;
    af0[0] = f2bf(a00.x); af0[1] = f2bf(a00.y);
    af0[2] = f2bf(a00.z); af0[3] = f2bf(a00.w);
    af0[4] = f2bf(a01.x); af0[5] = f2bf(a01.y);
    af0[6] = f2bf(a01.z); af0[7] = f2bf(a01.w);
    af1[0] = f2bf(a10.x); af1[1] = f2bf(a10.y);
    af1[2] = f2bf(a10.z); af1[3] = f2bf(a10.w);
    af1[4] = f2bf(a11.x); af1[5] = f2bf(a11.y);
    af1[6] = f2bf(a11.z); af1[7] = f2bf(a11.w);

    // ---- per-C-row metadata (rows rbase..rbase+3)
    int sp[4];
    float wq[4];
    int dl[4];
#pragma unroll
    for (int j = 0; j < 4; ++j) {
      const int jc = j0 + rbase + j;
      const int jcl = min(jc, E - 1);
      sp[j] = srcp[jcl];
      wq[j] = ewp[jcl];
      int lo = 0, hi = 32;
#pragma unroll
      for (int it = 0; it < 5; ++it) {
        const int mid = (lo + hi) >> 1;
        if (rp_s[mid] <= jc) lo = mid; else hi = mid;
      }
      dl[j] = lo;  // tail rows have zero C -> adding 0 anywhere is harmless
    }

#pragma unroll
    for (int c = 0; c < 8; ++c) {
      f32x4 C = {0.f, 0.f, 0.f, 0.f};
      C = __builtin_amdgcn_mfma_f32_16x16x32_bf16(af0, bf[c], C, 0, 0, 0);
      C = __builtin_amdgcn_mfma_f32_16x16x32_bf16(af1, bf[8 + c], C, 0, 0, 0);
#pragma unroll
      for (int j = 0; j < 4; ++j) {
        const float p = P[(size_t)sp[j] * H + (c << 4) + l15];
        atomicAdd(&acc[dl[j] * 132 + (c << 4) + l15], C[j] * wq[j] * p);
      }
    }
  }
  __syncthreads();

  // ---- epilogue: one write per node, optional fused LN + base + skip
  for (int n = w; n < 32; n += 4) {
    const int node = n0 + n;
    if (node >= N) break;
    const float v0 = acc[n * 132 + lane];
    const float v1 = acc[n * 132 + 64 + lane];
    const size_t i0 = (size_t)node * H + lane;
    if (FUSE_LN) {
      float s = v0 + v1, q = v0 * v0 + v1 * v1;
#pragma unroll
      for (int m = 32; m; m >>= 1) {
        s += __shfl_xor(s, m, 64);
        q += __shfl_xor(q, m, 64);
      }
      const float mu = s * 0.0078125f;
      const float var = q * 0.0078125f - mu * mu;
      const float rs = rsqrtf(var + 1e-5f);
      out[i0] = base[i0] + (v0 - mu) * rs * g[lane] + bb[lane] + skip[i0];
      out[i0 + 64] =
          base[i0 + 64] + (v1 - mu) * rs * g[lane + 64] + bb[lane + 64] + skip[i0 + 64];
    } else {
      out[i0] = v0;
      out[i0 + 64] = v1;
    }
  }
}

// ----------------------------------------------------------------- conv3d
__global__ __launch_bounds__(256) void conv3d(const float* __restrict__ Min,
                                              const float* __restrict__ Kt,
                                              const float* __restrict__ bias,
                                              float* __restrict__ Mout) {
  __shared__ float in_s[193 * 68];
  const int b = blockIdx.x >> 3;
  const int x = blockIdx.x & 7;
  const int t = threadIdx.x;
  const int tc = t & 15;
  const int tr = t >> 4;
  float acc[4][8];
  {
    const float4 bs0 = *(const float4*)(bias + tc * 8);
    const float4 bs1 = *(const float4*)(bias + tc * 8 + 4);
#pragma unroll
    for (int vi = 0; vi < 4; ++vi) {
      acc[vi][0] = bs0.x; acc[vi][1] = bs0.y; acc[vi][2] = bs0.z; acc[vi][3] = bs0.w;
      acc[vi][4] = bs1.x; acc[vi][5] = bs1.y; acc[vi][6] = bs1.z; acc[vi][7] = bs1.w;
    }
  }
  for (int u = t; u < 68; u += 256) in_s[192 * 68 + u] = 0.f;

  for (int pass = 0; pass < 2; ++pass) {
    __syncthreads();
#pragma unroll
    for (int it = 0; it < 12; ++it) {
      const int r = (t >> 4) + it * 16;
      const int c4 = (t & 15) * 4;
      const int xs = r >> 6;
      const int yz = r & 63;
      const int gx = x + xs - 1;
      float4 val = make_float4(0.f, 0.f, 0.f, 0.f);
      if (gx >= 0 && gx < 8) {
        const int row = (b * 8 + gx) * 64 + yz;
        val = *(const float4*)(Min + (size_t)row * H + pass * 64 + c4);
      }
      *(float4*)(in_s + r * 68 + c4) = val;
    }
    __syncthreads();

    for (int tap = 0; tap < 27; ++tap) {
      const int dx = tap / 9, dy = (tap / 3) % 3, dz = tap % 3;
      int rp[4];
#pragma unroll
      for (int vi = 0; vi < 4; ++vi) {
        const int v = tr * 4 + vi;
        const int y = v >> 3, z = v & 7;
        const int ny = y + dy - 1, nz = z + dz - 1;
        const bool ok = (ny >= 0 && ny < 8 && nz >= 0 && nz < 8);
        rp[vi] = ok ? (dx * 64 + ny * 8 + nz) * 68 : 192 * 68;
      }
      const float* wbase = Kt + ((size_t)tap * H + pass * 64) * H + tc * 8;
#pragma unroll 4
      for (int kk = 0; kk < 64; ++kk) {
        const float4 w0 = *(const float4*)(wbase + (size_t)kk * H);
        const float4 w1 = *(const float4*)(wbase + (size_t)kk * H + 4);
        float iv[4];
#pragma unroll
        for (int vi = 0; vi < 4; ++vi) iv[vi] = in_s[rp[vi] + kk];
#pragma unroll
        for (int vi = 0; vi < 4; ++vi) {
          acc[vi][0] += iv[vi] * w0.x; acc[vi][1] += iv[vi] * w0.y;
          acc[vi][2] += iv[vi] * w0.z; acc[vi][3] += iv[vi] * w0.w;
          acc[vi][4] += iv[vi] * w1.x; acc[vi][5] += iv[vi] * w1.y;
          acc[vi][6] += iv[vi] * w1.z; acc[vi][7] += iv[vi] * w1.w;
        }
      }
    }
  }
#pragma unroll
  for (int vi = 0; vi < 4; ++vi) {
    const int v = tr * 4 + vi;
    float* op = Mout + ((size_t)((b * 8 + x) * 64 + v)) * H + tc * 8;
    float4 o0 = {acc[vi][0], acc[vi][1], acc[vi][2], acc[vi][3]};
    float4 o1 = {acc[vi][4], acc[vi][5], acc[vi][6], acc[vi][7]};
    *(float4*)op = o0;
    *(float4*)(op + 4) = o1;
  }
}

// ------------------------------------------------------------------ driver
static inline void build_csr(const int* dst, const int* src, const float* ew,
                             int E, int N, int* cnt, int* bsum, int* bpre,
                             int* rowptr, int* cursor, int* perm, int* srcp,
                             float* ewp, hipStream_t stream) {
  const int NB = (N + 256) / 256;
  hipMemsetAsync(cnt, 0, (size_t)NB * 256 * sizeof(int), stream);
  k_hist<<<1024, 256, 0, stream>>>(dst, E, cnt);
  k_blocksum<<<NB, 256, 0, stream>>>(cnt, bsum);
  k_scan_bsum<<<1, 256, 0, stream>>>(bsum, bpre, NB);
  k_apply<<<NB, 256, 0, stream>>>(cnt, bpre, rowptr, cursor, N);
  k_perm<<<1024, 256, 0, stream>>>(dst, src, ew, E, cursor, perm, srcp, ewp);
}

extern "C" void kernel_launch(void* const* d_in, const int* in_sizes, int n_in,
                              void* d_out, int out_size, void* d_ws, size_t ws_size,
                              hipStream_t stream) {
  const float* a_x = (const float*)d_in[0];
  const float* m_x = (const float*)d_in[1];
  const int* aa_idx = (const int*)d_in[2];
  const int* a2m_src = (const int*)d_in[3];
  const int* a2m_dst = (const int*)d_in[4];
  const int* m2a_src = (const int*)d_in[5];
  const int* m2a_dst = (const int*)d_in[6];
  const float* aa_w = (const float*)d_in[7];
  const float* a2m_w = (const float*)d_in[8];
  const float* m2a_w = (const float*)d_in[9];
  const float* aa_ea = (const float*)d_in[10];
  const float* a2m_ea = (const float*)d_in[11];
  const float* m2a_ea = (const float*)d_in[12];
  const float* W_short = (const float*)d_in[13];
  const float* We_short = (const float*)d_in[14];
  const float* W_a2m = (const float*)d_in[15];
  const float* We_a2m = (const float*)d_in[16];
  const float* W_m2a = (const float*)d_in[17];
  const float* We_m2a = (const float*)d_in[18];
  const float* conv_k = (const float*)d_in[19];
  const float* conv_b = (const float*)d_in[20];
  const float* g_short = (const float*)d_in[21];
  const float* b_short = (const float*)d_in[22];
  const float* g_long = (const float*)d_in[23];
  const float* b_long = (const float*)d_in[24];
  const float* g_a2m = (const float*)d_in[25];
  const float* b_a2m = (const float*)d_in[26];
  const float* g_m2a = (const float*)d_in[27];
  const float* b_m2a = (const float*)d_in[28];

  const int NA = in_sizes[0] / H;
  const int NM = in_sizes[1] / H;
  const int E_AA = in_sizes[2] / 2;
  const int E_AM = in_sizes[3];
  const int E_MA = in_sizes[5];
  const int* aa_src = aa_idx;
  const int* aa_dst = aa_idx + E_AA;

  float* ws = (float*)d_ws;
  float* p_buf = ws;                         // NA*H
  float* m1_buf = p_buf + (size_t)NA * H;    // NM*H
  float* m2_buf = m1_buf + (size_t)NM * H;   // NM*H
  float* a2_buf = m2_buf + (size_t)NM * H;   // NA*H
  float* kt = a2_buf + (size_t)NA * H;       // 27*H*H
  float* ewp_aa = kt + (size_t)27 * H * H;   // E_AA
  float* ewp_a2m = ewp_aa + E_AA;            // E_AM
  float* ewp_m2a = ewp_a2m + E_AM;           // E_MA
  short* web_aa = (short*)(ewp_m2a + E_MA);  // 8192 bf16 each
  short* web_a2m = web_aa + 8192;
  short* web_m2a = web_a2m + 8192;
  int* iws = (int*)(web_m2a + 8192);
  int* perm_aa = iws;   iws += E_AA;
  int* perm_a2m = iws;  iws += E_AM;
  int* perm_m2a = iws;  iws += E_MA;
  int* srcp_aa = iws;   iws += E_AA;
  int* srcp_a2m = iws;  iws += E_AM;
  int* srcp_m2a = iws;  iws += E_MA;
  int* rp_aa = iws;     iws += NA + 1;
  int* rp_a2m = iws;    iws += NM + 1;
  int* rp_m2a = iws;    iws += NA + 1;
  const int PADN = ((NA + 256) / 256) * 256;
  int* cnt = iws;       iws += PADN;
  int* cursor = iws;    iws += PADN;
  int* bsum = iws;      iws += 256;
  int* bpre = iws;      iws += 256;

  float* out_a = (float*)d_out;
  float* out_m = out_a + (size_t)NA * H;

  // CSR builds
  build_csr(aa_dst, aa_src, aa_w, E_AA, NA, cnt, bsum, bpre, rp_aa, cursor,
            perm_aa, srcp_aa, ewp_aa, stream);
  build_csr(a2m_dst, a2m_src, a2m_w, E_AM, NM, cnt, bsum, bpre, rp_a2m, cursor,
            perm_a2m, srcp_a2m, ewp_a2m, stream);
  build_csr(m2a_dst, m2a_src, m2a_w, E_MA, NA, cnt, bsum, bpre, rp_m2a, cursor,
            perm_m2a, srcp_m2a, ewp_m2a, stream);

  // weight prep
  pack_we<<<4, 256, 0, stream>>>(We_short, web_aa);
  pack_we<<<4, 256, 0, stream>>>(We_a2m, web_a2m);
  pack_we<<<4, 256, 0, stream>>>(We_m2a, web_m2a);
  transpose_k<<<(H * H * 27 + 255) / 256, 256, 0, stream>>>(conv_k, kt);

  ln_rows<<<NM, 128, 0, stream>>>(m_x, g_long, b_long, m1_buf, NM);

  // P_short = LN(a_x) @ W_short
  proj_kernel<true><<<(NA + 63) / 64, 256, 0, stream>>>(a_x, W_short, g_short,
                                                        b_short, p_buf, NA);
  // a = gather_aa(P_short) (raw)
  gather_mfma<false><<<(NA + 31) / 32, 256, 0, stream>>>(
      p_buf, web_aa, aa_ea, perm_aa, srcp_aa, ewp_aa, rp_aa, E_AA, NA, nullptr,
      nullptr, nullptr, nullptr, a2_buf);
  // m = conv3d(LN(m_x))
  conv3d<<<(NM / 64), 256, 0, stream>>>(m1_buf, kt, conv_b, m2_buf);

  // P_a2m = a @ W_a2m
  proj_kernel<false><<<(NA + 63) / 64, 256, 0, stream>>>(a2_buf, W_a2m, nullptr,
                                                         nullptr, p_buf, NA);
  // out_m = m + LN(gather_a2m(P_a2m)) + m_x
  gather_mfma<true><<<(NM + 31) / 32, 256, 0, stream>>>(
      p_buf, web_a2m, a2m_ea, perm_a2m, srcp_a2m, ewp_a2m, rp_a2m, E_AM, NM,
      m2_buf, m_x, g_a2m, b_a2m, out_m);
  // P_m2a = m @ W_m2a
  proj_kernel<false><<<(NM + 63) / 64, 256, 0, stream>>>(m2_buf, W_m2a, nullptr,
                                                         nullptr, m1_buf, NM);
  // out_a = a + LN(gather_m2a(P_m2a)) + a_x
  gather_mfma<true><<<(NA + 31) / 32, 256, 0, stream>>>(
      m1_buf, web_m2a, m2a_ea, perm_m2a, srcp_m2a, ewp_m2a, rp_m2a, E_MA, NA,
      a2_buf, a_x, g_m2a, b_m2a, out_a);
}

// Round 4
// 2009.659 us; speedup vs baseline: 1.3130x; 1.0185x over previous
//
#include <hip/hip_runtime.h>
#include <hip/hip_bf16.h>

#define H 128
#define RBF 64

typedef __attribute__((ext_vector_type(8))) short bf16x8;
typedef __attribute__((ext_vector_type(4))) float f32x4;

__device__ inline short f2bf(float f) {
  union { float f; unsigned u; } v; v.f = f;
  const unsigned r = (v.u + 0x7FFFu + ((v.u >> 16) & 1u)) >> 16;
  return (short)r;
}

// ---------------------------------------------------------------- utilities
__global__ __launch_bounds__(128) void ln_rows(const float* __restrict__ X,
                                               const float* __restrict__ g,
                                               const float* __restrict__ bb,
                                               float* __restrict__ Y, int N) {
  __shared__ float sh[4];
  const int row = blockIdx.x;
  const int j = threadIdx.x;
  float x = X[(size_t)row * H + j];
  float s = x, q = x * x;
#pragma unroll
  for (int m = 32; m; m >>= 1) {
    s += __shfl_xor(s, m, 64);
    q += __shfl_xor(q, m, 64);
  }
  if ((j & 63) == 0) { sh[(j >> 6) * 2] = s; sh[(j >> 6) * 2 + 1] = q; }
  __syncthreads();
  s = sh[0] + sh[2];
  q = sh[1] + sh[3];
  const float mu = s * 0.0078125f;
  const float var = q * 0.0078125f - mu * mu;
  const float rs = rsqrtf(var + 1e-5f);
  Y[(size_t)row * H + j] = (x - mu) * rs * g[j] + bb[j];
}

// conv_k (o,i,dx,dy,dz) -> Kt[tap][i][o]
__global__ void transpose_k(const float* __restrict__ K, float* __restrict__ Kt) {
  const int idx = blockIdx.x * 256 + threadIdx.x;
  const int total = H * H * 27;
  if (idx >= total) return;
  const int tap = idx % 27;
  const int rem = idx / 27;
  const int i = rem % H;
  const int o = rem / H;
  Kt[((size_t)tap * H + i) * H + o] = K[idx];
}

// We[64][128] f32 -> frag-layout bf16: Web[((h*8+c)*64+lane)*8+j]
__global__ __launch_bounds__(256) void pack_we(const float* __restrict__ We,
                                               short* __restrict__ Web) {
  const int id = blockIdx.x * 256 + threadIdx.x;
  if (id >= 1024) return;
  const int f = id >> 6, l = id & 63;
  const int h = f >> 3, c = f & 7;
  const int col = (c << 4) + (l & 15);
  const int k0 = h * 32 + (l >> 4) * 8;
  short* o = Web + (size_t)id * 8;
#pragma unroll
  for (int j = 0; j < 8; ++j) o[j] = f2bf(We[(k0 + j) * H + col]);
}

// ----------------------------------------------- counting-sort (CSR builder)
__global__ __launch_bounds__(256) void k_hist(const int* __restrict__ dst, int E,
                                              int* __restrict__ cnt) {
  int e = blockIdx.x * 256 + threadIdx.x;
  const int stride = gridDim.x * 256;
  for (; e < E; e += stride) atomicAdd(&cnt[dst[e]], 1);
}

__global__ __launch_bounds__(256) void k_blocksum(const int* __restrict__ cnt,
                                                  int* __restrict__ bsum) {
  __shared__ int sh[256];
  const int t = threadIdx.x;
  sh[t] = cnt[blockIdx.x * 256 + t];
  __syncthreads();
#pragma unroll
  for (int o = 128; o; o >>= 1) {
    if (t < o) sh[t] += sh[t + o];
    __syncthreads();
  }
  if (!t) bsum[blockIdx.x] = sh[0];
}

__global__ __launch_bounds__(256) void k_scan_bsum(const int* __restrict__ bsum,
                                                   int* __restrict__ bpre, int NB) {
  __shared__ int sh[256];
  const int t = threadIdx.x;
  const int v = (t < NB) ? bsum[t] : 0;
  sh[t] = v;
  __syncthreads();
  for (int o = 1; o < 256; o <<= 1) {
    const int u = (t >= o) ? sh[t - o] : 0;
    __syncthreads();
    sh[t] += u;
    __syncthreads();
  }
  if (t < NB) bpre[t] = sh[t] - v;
}

__global__ __launch_bounds__(256) void k_apply(const int* __restrict__ cnt,
                                               const int* __restrict__ bpre,
                                               int* __restrict__ rowptr,
                                               int* __restrict__ cursor, int N) {
  __shared__ int sh[256];
  const int t = threadIdx.x;
  const int i = blockIdx.x * 256 + t;
  const int v = cnt[i];
  sh[t] = v;
  __syncthreads();
  for (int o = 1; o < 256; o <<= 1) {
    const int u = (t >= o) ? sh[t - o] : 0;
    __syncthreads();
    sh[t] += u;
    __syncthreads();
  }
  const int excl = sh[t] - v + bpre[blockIdx.x];
  if (i <= N) {
    rowptr[i] = excl;
    if (i < N) cursor[i] = excl;
  }
}

// also pre-permute src and ew to kill double indirection in the gather
__global__ __launch_bounds__(256) void k_perm(const int* __restrict__ dst,
                                              const int* __restrict__ src,
                                              const float* __restrict__ ew, int E,
                                              int* __restrict__ cursor,
                                              int* __restrict__ perm,
                                              int* __restrict__ srcp,
                                              float* __restrict__ ewp) {
  int e = blockIdx.x * 256 + threadIdx.x;
  const int stride = gridDim.x * 256;
  for (; e < E; e += stride) {
    const int p = atomicAdd(&cursor[dst[e]], 1);
    perm[p] = e;
    srcp[p] = src[e];
    ewp[p] = ew[e];
  }
}

// ------------------------------------------- node projection: Y = [LN](X) @ W
template <bool DO_LN>
__global__ __launch_bounds__(256) void proj_kernel(const float* __restrict__ X,
                                                   const float* __restrict__ W,
                                                   const float* __restrict__ g,
                                                   const float* __restrict__ bb,
                                                   float* __restrict__ Y, int N) {
  __shared__ float At[128 * 68];
  const int row0 = blockIdx.x * 64;
  const int t = threadIdx.x;
  const int lk = (t & 31) * 4;
  const int lr = t >> 5;
  float4 g4 = {0, 0, 0, 0}, b4 = {0, 0, 0, 0};
  if (DO_LN) {
    g4 = *(const float4*)(g + lk);
    b4 = *(const float4*)(bb + lk);
  }
#pragma unroll
  for (int p = 0; p < 8; ++p) {
    const int r = lr + p * 8;
    const int row = row0 + r;
    float4 xv = make_float4(0.f, 0.f, 0.f, 0.f);
    if (row < N) xv = *(const float4*)(X + (size_t)row * H + lk);
    if (DO_LN) {
      float s = xv.x + xv.y + xv.z + xv.w;
      float q = xv.x * xv.x + xv.y * xv.y + xv.z * xv.z + xv.w * xv.w;
#pragma unroll
      for (int m = 16; m; m >>= 1) {
        s += __shfl_xor(s, m, 64);
        q += __shfl_xor(q, m, 64);
      }
      const float mu = s * 0.0078125f;
      const float var = q * 0.0078125f - mu * mu;
      const float rs = rsqrtf(var + 1e-5f);
      xv.x = (xv.x - mu) * rs * g4.x + b4.x;
      xv.y = (xv.y - mu) * rs * g4.y + b4.y;
      xv.z = (xv.z - mu) * rs * g4.z + b4.z;
      xv.w = (xv.w - mu) * rs * g4.w + b4.w;
    }
    At[(lk + 0) * 68 + r] = xv.x;
    At[(lk + 1) * 68 + r] = xv.y;
    At[(lk + 2) * 68 + r] = xv.z;
    At[(lk + 3) * 68 + r] = xv.w;
  }
  __syncthreads();
  const int tc = t & 15;
  const int tr = t >> 4;
  float acc[4][8];
#pragma unroll
  for (int i = 0; i < 4; ++i)
#pragma unroll
    for (int c = 0; c < 8; ++c) acc[i][c] = 0.f;
  const float* wbase = W + tc * 8;
#pragma unroll 4
  for (int k = 0; k < 128; ++k) {
    const float4 a4 = *(const float4*)(At + k * 68 + tr * 4);
    const float4 w0 = *(const float4*)(wbase + k * H);
    const float4 w1 = *(const float4*)(wbase + k * H + 4);
    const float av[4] = {a4.x, a4.y, a4.z, a4.w};
#pragma unroll
    for (int i = 0; i < 4; ++i) {
      acc[i][0] += av[i] * w0.x; acc[i][1] += av[i] * w0.y;
      acc[i][2] += av[i] * w0.z; acc[i][3] += av[i] * w0.w;
      acc[i][4] += av[i] * w1.x; acc[i][5] += av[i] * w1.y;
      acc[i][6] += av[i] * w1.z; acc[i][7] += av[i] * w1.w;
    }
  }
#pragma unroll
  for (int i = 0; i < 4; ++i) {
    const int row = row0 + tr * 4 + i;
    if (row < N) {
      float4 o0 = {acc[i][0], acc[i][1], acc[i][2], acc[i][3]};
      float4 o1 = {acc[i][4], acc[i][5], acc[i][6], acc[i][7]};
      float* yp = Y + (size_t)row * H + tc * 8;
      *(float4*)yp = o0;
      *(float4*)(yp + 4) = o1;
    }
  }
}

// ----------------------------------------- tiled MFMA edge gather (CSR, LDS)
// Block owns 32 dst nodes. 16-edge tiles: F = bf16(ea_tile) @ Web via MFMA;
// msg = F * ew * P[src]; hardware ds_add_f32 into acc[32][132]; fused LN.
template <bool FUSE_LN>
__global__ __launch_bounds__(256, 2) void gather_mfma(
    const float* __restrict__ P, const short* __restrict__ Web,
    const float* __restrict__ ea, const int* __restrict__ perm,
    const int* __restrict__ srcp, const float* __restrict__ ewp,
    const int* __restrict__ rowptr, int E, int N,
    const float* __restrict__ base, const float* __restrict__ skip,
    const float* __restrict__ g, const float* __restrict__ bb,
    float* __restrict__ out) {
  __shared__ float acc[32 * 132];
  __shared__ int rp_s[33];
  const int t = threadIdx.x;
  const int w = t >> 6, lane = t & 63;
  const int n0 = blockIdx.x * 32;
  if (t < 33) rp_s[t] = rowptr[min(n0 + t, N)];
  for (int u = t; u < 32 * 132; u += 256) acc[u] = 0.f;
  __syncthreads();
  const int beg = rp_s[0], end = rp_s[32];
  const int ntiles = (end - beg + 15) >> 4;

  // B fragments: 16 x bf16x8 (64 VGPRs), frag f = h*8+c
  bf16x8 bf[16];
#pragma unroll
  for (int f = 0; f < 16; ++f)
    bf[f] = *(const bf16x8*)(Web + ((size_t)((f << 6) + lane)) * 8);

  const int l15 = lane & 15;
  const int lg = lane >> 4;
  const int rbase = lg * 4;

  for (int tt = w; tt < ntiles; tt += 4) {
    const int j0 = beg + (tt << 4);
    // ---- A fragments: lane holds ea row (j0 + l15), k = lg*8.. (+32 half)
    const int ja = j0 + l15;
    const bool av = ja < end;
    const int pe = perm[min(ja, E - 1)];
    const float* ear = ea + (size_t)pe * RBF + lg * 8;
    float4 a00 = make_float4(0.f, 0.f, 0.f, 0.f);
    float4 a01 = a00, a10 = a00, a11 = a00;
    if (av) {
      a00 = *(const float4*)(ear);
      a01 = *(const float4*)(ear + 4);
      a10 = *(const float4*)(ear + 32);
      a11 = *(const float4*)(ear + 36);
    }
    bf16x8 af0, af1;
    af0[0] = f2bf(a00.x); af0[1] = f2bf(a00.y);
    af0[2] = f2bf(a00.z); af0[3] = f2bf(a00.w);
    af0[4] = f2bf(a01.x); af0[5] = f2bf(a01.y);
    af0[6] = f2bf(a01.z); af0[7] = f2bf(a01.w);
    af1[0] = f2bf(a10.x); af1[1] = f2bf(a10.y);
    af1[2] = f2bf(a10.z); af1[3] = f2bf(a10.w);
    af1[4] = f2bf(a11.x); af1[5] = f2bf(a11.y);
    af1[6] = f2bf(a11.z); af1[7] = f2bf(a11.w);

    // ---- per-C-row metadata (rows rbase..rbase+3)
    int sp[4];
    float wq[4];
    int dl[4];
#pragma unroll
    for (int j = 0; j < 4; ++j) {
      const int jc = j0 + rbase + j;
      const int jcl = min(jc, E - 1);
      sp[j] = srcp[jcl];
      wq[j] = ewp[jcl];
      int lo = 0, hi = 32;
#pragma unroll
      for (int it = 0; it < 5; ++it) {
        const int mid = (lo + hi) >> 1;
        if (rp_s[mid] <= jc) lo = mid; else hi = mid;
      }
      dl[j] = lo;  // tail rows have zero C -> adding 0 anywhere is harmless
    }

#pragma unroll
    for (int c = 0; c < 8; ++c) {
      f32x4 C = {0.f, 0.f, 0.f, 0.f};
      C = __builtin_amdgcn_mfma_f32_16x16x32_bf16(af0, bf[c], C, 0, 0, 0);
      C = __builtin_amdgcn_mfma_f32_16x16x32_bf16(af1, bf[8 + c], C, 0, 0, 0);
#pragma unroll
      for (int j = 0; j < 4; ++j) {
        const float p = P[(size_t)sp[j] * H + (c << 4) + l15];
        // HW ds_add_f32 (plain atomicAdd on LDS f32 lowers to a CAS loop!)
        unsafeAtomicAdd(&acc[dl[j] * 132 + (c << 4) + l15], C[j] * wq[j] * p);
      }
    }
  }
  __syncthreads();

  // ---- epilogue: one write per node, optional fused LN + base + skip
  for (int n = w; n < 32; n += 4) {
    const int node = n0 + n;
    if (node >= N) break;
    const float v0 = acc[n * 132 + lane];
    const float v1 = acc[n * 132 + 64 + lane];
    const size_t i0 = (size_t)node * H + lane;
    if (FUSE_LN) {
      float s = v0 + v1, q = v0 * v0 + v1 * v1;
#pragma unroll
      for (int m = 32; m; m >>= 1) {
        s += __shfl_xor(s, m, 64);
        q += __shfl_xor(q, m, 64);
      }
      const float mu = s * 0.0078125f;
      const float var = q * 0.0078125f - mu * mu;
      const float rs = rsqrtf(var + 1e-5f);
      out[i0] = base[i0] + (v0 - mu) * rs * g[lane] + bb[lane] + skip[i0];
      out[i0 + 64] =
          base[i0 + 64] + (v1 - mu) * rs * g[lane + 64] + bb[lane + 64] + skip[i0 + 64];
    } else {
      out[i0] = v0;
      out[i0 + 64] = v1;
    }
  }
}

// ----------------------------------------------------------------- conv3d
__global__ __launch_bounds__(256) void conv3d(const float* __restrict__ Min,
                                              const float* __restrict__ Kt,
                                              const float* __restrict__ bias,
                                              float* __restrict__ Mout) {
  __shared__ float in_s[193 * 68];
  const int b = blockIdx.x >> 3;
  const int x = blockIdx.x & 7;
  const int t = threadIdx.x;
  const int tc = t & 15;
  const int tr = t >> 4;
  float acc[4][8];
  {
    const float4 bs0 = *(const float4*)(bias + tc * 8);
    const float4 bs1 = *(const float4*)(bias + tc * 8 + 4);
#pragma unroll
    for (int vi = 0; vi < 4; ++vi) {
      acc[vi][0] = bs0.x; acc[vi][1] = bs0.y; acc[vi][2] = bs0.z; acc[vi][3] = bs0.w;
      acc[vi][4] = bs1.x; acc[vi][5] = bs1.y; acc[vi][6] = bs1.z; acc[vi][7] = bs1.w;
    }
  }
  for (int u = t; u < 68; u += 256) in_s[192 * 68 + u] = 0.f;

  for (int pass = 0; pass < 2; ++pass) {
    __syncthreads();
#pragma unroll
    for (int it = 0; it < 12; ++it) {
      const int r = (t >> 4) + it * 16;
      const int c4 = (t & 15) * 4;
      const int xs = r >> 6;
      const int yz = r & 63;
      const int gx = x + xs - 1;
      float4 val = make_float4(0.f, 0.f, 0.f, 0.f);
      if (gx >= 0 && gx < 8) {
        const int row = (b * 8 + gx) * 64 + yz;
        val = *(const float4*)(Min + (size_t)row * H + pass * 64 + c4);
      }
      *(float4*)(in_s + r * 68 + c4) = val;
    }
    __syncthreads();

    for (int tap = 0; tap < 27; ++tap) {
      const int dx = tap / 9, dy = (tap / 3) % 3, dz = tap % 3;
      int rp[4];
#pragma unroll
      for (int vi = 0; vi < 4; ++vi) {
        const int v = tr * 4 + vi;
        const int y = v >> 3, z = v & 7;
        const int ny = y + dy - 1, nz = z + dz - 1;
        const bool ok = (ny >= 0 && ny < 8 && nz >= 0 && nz < 8);
        rp[vi] = ok ? (dx * 64 + ny * 8 + nz) * 68 : 192 * 68;
      }
      const float* wbase = Kt + ((size_t)tap * H + pass * 64) * H + tc * 8;
#pragma unroll 4
      for (int kk = 0; kk < 64; ++kk) {
        const float4 w0 = *(const float4*)(wbase + (size_t)kk * H);
        const float4 w1 = *(const float4*)(wbase + (size_t)kk * H + 4);
        float iv[4];
#pragma unroll
        for (int vi = 0; vi < 4; ++vi) iv[vi] = in_s[rp[vi] + kk];
#pragma unroll
        for (int vi = 0; vi < 4; ++vi) {
          acc[vi][0] += iv[vi] * w0.x; acc[vi][1] += iv[vi] * w0.y;
          acc[vi][2] += iv[vi] * w0.z; acc[vi][3] += iv[vi] * w0.w;
          acc[vi][4] += iv[vi] * w1.x; acc[vi][5] += iv[vi] * w1.y;
          acc[vi][6] += iv[vi] * w1.z; acc[vi][7] += iv[vi] * w1.w;
        }
      }
    }
  }
#pragma unroll
  for (int vi = 0; vi < 4; ++vi) {
    const int v = tr * 4 + vi;
    float* op = Mout + ((size_t)((b * 8 + x) * 64 + v)) * H + tc * 8;
    float4 o0 = {acc[vi][0], acc[vi][1], acc[vi][2], acc[vi][3]};
    float4 o1 = {acc[vi][4], acc[vi][5], acc[vi][6], acc[vi][7]};
    *(float4*)op = o0;
    *(float4*)(op + 4) = o1;
  }
}

// ------------------------------------------------------------------ driver
static inline void build_csr(const int* dst, const int* src, const float* ew,
                             int E, int N, int* cnt, int* bsum, int* bpre,
                             int* rowptr, int* cursor, int* perm, int* srcp,
                             float* ewp, hipStream_t stream) {
  const int NB = (N + 256) / 256;
  hipMemsetAsync(cnt, 0, (size_t)NB * 256 * sizeof(int), stream);
  k_hist<<<1024, 256, 0, stream>>>(dst, E, cnt);
  k_blocksum<<<NB, 256, 0, stream>>>(cnt, bsum);
  k_scan_bsum<<<1, 256, 0, stream>>>(bsum, bpre, NB);
  k_apply<<<NB, 256, 0, stream>>>(cnt, bpre, rowptr, cursor, N);
  k_perm<<<1024, 256, 0, stream>>>(dst, src, ew, E, cursor, perm, srcp, ewp);
}

extern "C" void kernel_launch(void* const* d_in, const int* in_sizes, int n_in,
                              void* d_out, int out_size, void* d_ws, size_t ws_size,
                              hipStream_t stream) {
  const float* a_x = (const float*)d_in[0];
  const float* m_x = (const float*)d_in[1];
  const int* aa_idx = (const int*)d_in[2];
  const int* a2m_src = (const int*)d_in[3];
  const int* a2m_dst = (const int*)d_in[4];
  const int* m2a_src = (const int*)d_in[5];
  const int* m2a_dst = (const int*)d_in[6];
  const float* aa_w = (const float*)d_in[7];
  const float* a2m_w = (const float*)d_in[8];
  const float* m2a_w = (const float*)d_in[9];
  const float* aa_ea = (const float*)d_in[10];
  const float* a2m_ea = (const float*)d_in[11];
  const float* m2a_ea = (const float*)d_in[12];
  const float* W_short = (const float*)d_in[13];
  const float* We_short = (const float*)d_in[14];
  const float* W_a2m = (const float*)d_in[15];
  const float* We_a2m = (const float*)d_in[16];
  const float* W_m2a = (const float*)d_in[17];
  const float* We_m2a = (const float*)d_in[18];
  const float* conv_k = (const float*)d_in[19];
  const float* conv_b = (const float*)d_in[20];
  const float* g_short = (const float*)d_in[21];
  const float* b_short = (const float*)d_in[22];
  const float* g_long = (const float*)d_in[23];
  const float* b_long = (const float*)d_in[24];
  const float* g_a2m = (const float*)d_in[25];
  const float* b_a2m = (const float*)d_in[26];
  const float* g_m2a = (const float*)d_in[27];
  const float* b_m2a = (const float*)d_in[28];

  const int NA = in_sizes[0] / H;
  const int NM = in_sizes[1] / H;
  const int E_AA = in_sizes[2] / 2;
  const int E_AM = in_sizes[3];
  const int E_MA = in_sizes[5];
  const int* aa_src = aa_idx;
  const int* aa_dst = aa_idx + E_AA;

  float* ws = (float*)d_ws;
  float* p_buf = ws;                         // NA*H
  float* m1_buf = p_buf + (size_t)NA * H;    // NM*H
  float* m2_buf = m1_buf + (size_t)NM * H;   // NM*H
  float* a2_buf = m2_buf + (size_t)NM * H;   // NA*H
  float* kt = a2_buf + (size_t)NA * H;       // 27*H*H
  float* ewp_aa = kt + (size_t)27 * H * H;   // E_AA
  float* ewp_a2m = ewp_aa + E_AA;            // E_AM
  float* ewp_m2a = ewp_a2m + E_AM;           // E_MA
  short* web_aa = (short*)(ewp_m2a + E_MA);  // 8192 bf16 each
  short* web_a2m = web_aa + 8192;
  short* web_m2a = web_a2m + 8192;
  int* iws = (int*)(web_m2a + 8192);
  int* perm_aa = iws;   iws += E_AA;
  int* perm_a2m = iws;  iws += E_AM;
  int* perm_m2a = iws;  iws += E_MA;
  int* srcp_aa = iws;   iws += E_AA;
  int* srcp_a2m = iws;  iws += E_AM;
  int* srcp_m2a = iws;  iws += E_MA;
  int* rp_aa = iws;     iws += NA + 1;
  int* rp_a2m = iws;    iws += NM + 1;
  int* rp_m2a = iws;    iws += NA + 1;
  const int PADN = ((NA + 256) / 256) * 256;
  int* cnt = iws;       iws += PADN;
  int* cursor = iws;    iws += PADN;
  int* bsum = iws;      iws += 256;
  int* bpre = iws;      iws += 256;

  float* out_a = (float*)d_out;
  float* out_m = out_a + (size_t)NA * H;

  // CSR builds
  build_csr(aa_dst, aa_src, aa_w, E_AA, NA, cnt, bsum, bpre, rp_aa, cursor,
            perm_aa, srcp_aa, ewp_aa, stream);
  build_csr(a2m_dst, a2m_src, a2m_w, E_AM, NM, cnt, bsum, bpre, rp_a2m, cursor,
            perm_a2m, srcp_a2m, ewp_a2m, stream);
  build_csr(m2a_dst, m2a_src, m2a_w, E_MA, NA, cnt, bsum, bpre, rp_m2a, cursor,
            perm_m2a, srcp_m2a, ewp_m2a, stream);

  // weight prep
  pack_we<<<4, 256, 0, stream>>>(We_short, web_aa);
  pack_we<<<4, 256, 0, stream>>>(We_a2m, web_a2m);
  pack_we<<<4, 256, 0, stream>>>(We_m2a, web_m2a);
  transpose_k<<<(H * H * 27 + 255) / 256, 256, 0, stream>>>(conv_k, kt);

  ln_rows<<<NM, 128, 0, stream>>>(m_x, g_long, b_long, m1_buf, NM);

  // P_short = LN(a_x) @ W_short
  proj_kernel<true><<<(NA + 63) / 64, 256, 0, stream>>>(a_x, W_short, g_short,
                                                        b_short, p_buf, NA);
  // a = gather_aa(P_short) (raw)
  gather_mfma<false><<<(NA + 31) / 32, 256, 0, stream>>>(
      p_buf, web_aa, aa_ea, perm_aa, srcp_aa, ewp_aa, rp_aa, E_AA, NA, nullptr,
      nullptr, nullptr, nullptr, a2_buf);
  // m = conv3d(LN(m_x))
  conv3d<<<(NM / 64), 256, 0, stream>>>(m1_buf, kt, conv_b, m2_buf);

  // P_a2m = a @ W_a2m
  proj_kernel<false><<<(NA + 63) / 64, 256, 0, stream>>>(a2_buf, W_a2m, nullptr,
                                                         nullptr, p_buf, NA);
  // out_m = m + LN(gather_a2m(P_a2m)) + m_x
  gather_mfma<true><<<(NM + 31) / 32, 256, 0, stream>>>(
      p_buf, web_a2m, a2m_ea, perm_a2m, srcp_a2m, ewp_a2m, rp_a2m, E_AM, NM,
      m2_buf, m_x, g_a2m, b_a2m, out_m);
  // P_m2a = m @ W_m2a
  proj_kernel<false><<<(NM + 63) / 64, 256, 0, stream>>>(m2_buf, W_m2a, nullptr,
                                                         nullptr, m1_buf, NM);
  // out_a = a + LN(gather_m2a(P_m2a)) + a_x
  gather_mfma<true><<<(NA + 31) / 32, 256, 0, stream>>>(
      m1_buf, web_m2a, m2a_ea, perm_m2a, srcp_m2a, ewp_m2a, rp_m2a, E_MA, NA,
      a2_buf, a_x, g_m2a, b_m2a, out_a);
}